// Round 1
// baseline (449.698 us; speedup 1.0000x reference)
//
#include <hip/hip_runtime.h>
#include <hip/hip_bf16.h>
#include <stdint.h>

#define S 2048
#define HID 2048
#define NH 16
#define HD 128

typedef short short8 __attribute__((ext_vector_type(8)));
typedef float f32x4 __attribute__((ext_vector_type(4)));

__device__ __forceinline__ ushort f2bf(float x) {
  uint32_t u = __builtin_bit_cast(uint32_t, x);
  if ((u & 0x7fffffffu) > 0x7f800000u) return (ushort)((u >> 16) | 0x40);  // quiet NaN
  uint32_t r = u + 0x7fffu + ((u >> 16) & 1u);                             // RNE
  return (ushort)(r >> 16);
}
__device__ __forceinline__ float bf2f(ushort u) {
  union { uint32_t i; float f; } c; c.i = ((uint32_t)u) << 16; return c.f;
}

// async global->LDS, 16B per lane; LDS dest must be wave-uniform (HW adds lane*16)
__device__ __forceinline__ void glds16(const ushort* g, ushort* l) {
  __builtin_amdgcn_global_load_lds((const __attribute__((address_space(1))) uint32_t*)g,
                                   (__attribute__((address_space(3))) uint32_t*)l, 16, 0, 0);
}

// D += A*B, 16x16x32 bf16 (A: row=lane&15, k=(lane>>4)*8+j; B: col=lane&15, same k;
// D: col=lane&15, row=(lane>>4)*4+reg)  -- inline asm to avoid builtin type ambiguity
__device__ __forceinline__ void mfma16(f32x4& d, short8 a, short8 b) {
  asm("v_mfma_f32_16x16x32_bf16 %0, %1, %2, %0" : "+v"(d) : "v"(a), "v"(b));
}

__global__ __launch_bounds__(256) void cast_f32_bf16_k(const float* __restrict__ in,
                                                       ushort* __restrict__ out, int n4) {
  int i = blockIdx.x * 256 + threadIdx.x;
  if (i >= n4) return;
  float4 v = ((const float4*)in)[i];
  ushort4 o;
  o.x = f2bf(v.x); o.y = f2bf(v.y); o.z = f2bf(v.z); o.w = f2bf(v.w);
  ((ushort4*)out)[i] = o;
}

// C[m,n] = sum_k A[m,k]*B[n,k]; A:[M][K] bf16, B:[N][K] bf16.
// OUTF32: store f32(bf16(acc)) else bf16. NSPLIT: N spans multiple [M][2048] buffers.
// 128x128 tile, BK=64, XOR slot-swizzle (slot ^= row&7 within 128B rows).
template <int OUTF32, int NSPLIT>
__global__ __launch_bounds__(256)
void gemm_bt_k(const ushort* __restrict__ A, const ushort* __restrict__ B,
               void* __restrict__ C, int M, int N, int K) {
  __shared__ __align__(16) ushort ldsA[128 * 64];
  __shared__ __align__(16) ushort ldsB[128 * 64];
  const int tid = threadIdx.x, lane = tid & 63, wid = tid >> 6;
  const int g = lane >> 4, c = lane & 15;
  const int wr = wid >> 1, wc = wid & 1;
  const long m0 = (long)blockIdx.y * 128, n0 = (long)blockIdx.x * 128;
  const int srow = lane >> 3, sslot = lane & 7;

  f32x4 acc[4][4] = {};

  for (int k0 = 0; k0 < K; k0 += 64) {
#pragma unroll
    for (int i = 0; i < 4; ++i) {
      int ii = wid * 4 + i;
      int rt = ii * 8 + srow;
      int col = ((sslot ^ (rt & 7)) << 3) + k0;
      glds16(A + (m0 + rt) * (long)K + col, ldsA + ii * 512);
      glds16(B + (n0 + rt) * (long)K + col, ldsB + ii * 512);
    }
    __syncthreads();
#pragma unroll
    for (int kk = 0; kk < 2; ++kk) {
      short8 af[4], bfr[4];
#pragma unroll
      for (int m = 0; m < 4; ++m) {
        int row = wr * 64 + m * 16 + c;
        af[m] = *(const short8*)(ldsA + row * 64 + (((kk * 4 + g) ^ (row & 7)) << 3));
      }
#pragma unroll
      for (int n = 0; n < 4; ++n) {
        int row = wc * 64 + n * 16 + c;
        bfr[n] = *(const short8*)(ldsB + row * 64 + (((kk * 4 + g) ^ (row & 7)) << 3));
      }
#pragma unroll
      for (int m = 0; m < 4; ++m)
#pragma unroll
        for (int n = 0; n < 4; ++n) mfma16(acc[m][n], af[m], bfr[n]);
    }
    __syncthreads();
  }
  asm volatile("s_nop 7\n\ts_nop 7");
#pragma unroll
  for (int m = 0; m < 4; ++m) {
#pragma unroll
    for (int r = 0; r < 4; ++r) {
      long grow = m0 + wr * 64 + m * 16 + g * 4 + r;
#pragma unroll
      for (int n = 0; n < 4; ++n) {
        long gcol = n0 + wc * 64 + n * 16 + c;
        long idx;
        if (NSPLIT) idx = ((gcol >> 11) << 22) + (grow << 11) + (gcol & 2047);
        else        idx = grow * N + gcol;
        float v = acc[m][n][r];
        if (OUTF32) ((float*)C)[idx] = bf2f(f2bf(v));
        else        ((ushort*)C)[idx] = f2bf(v);
      }
    }
  }
}

__global__ __launch_bounds__(256)
void transpose_bf16_k(const ushort* __restrict__ in, ushort* __restrict__ out) {
  __shared__ __align__(16) ushort t[64][72];
  const int tid = threadIdx.x;
  const long bx = (long)blockIdx.x * 64;  // col tile of in (dglob)
  const long by = (long)blockIdx.y * 64;  // row tile of in (s)
#pragma unroll
  for (int i = 0; i < 2; ++i) {
    int row = (tid >> 3) + i * 32;
    int col = (tid & 7) * 8;
    *(short8*)(&t[row][col]) = *(const short8*)(in + (by + row) * 2048 + bx + col);
  }
  __syncthreads();
#pragma unroll
  for (int i = 0; i < 2; ++i) {
    int orow = (tid >> 3) + i * 32;
    int ocol = (tid & 7) * 8;
    short8 v;
#pragma unroll
    for (int j = 0; j < 8; ++j) v[j] = (short)t[ocol + j][orow];
    *(short8*)(out + (bx + orow) * 2048 + by + ocol) = v;
  }
}

// Flash attention. Grid: (S/64, NH, 2). Block 256 = 4 waves x 16 q-rows.
// Kp: [S][HID] bf16 (k at head offset), Vt: [HID][S] bf16 (pre-transposed).
// Writes out_flat[2*q+blk][h*128+d] bf16.
__global__ __launch_bounds__(256)
void attn_k(const ushort* __restrict__ Qself, const ushort* __restrict__ Qcross,
            const ushort* __restrict__ Kp, const ushort* __restrict__ Vt,
            const float* __restrict__ mask, ushort* __restrict__ outf) {
  __shared__ __align__(16) ushort ldsK[64 * 128];   // [kv][d], 256B rows, slot^=(row&15)
  __shared__ __align__(16) ushort ldsV[128 * 64];   // [d][kv], 128B rows, slot^=(row&7)
  __shared__ __align__(16) ushort ldsP[4][16 * 64]; // per-wave P, 128B rows, slot^=(row&7)
  const int tid = threadIdx.x, lane = tid & 63, wid = tid >> 6;
  const int g = lane >> 4, c = lane & 15;
  const int h = blockIdx.y, blk = blockIdx.z;
  const ushort* Qp = blk ? Qcross : Qself;
  const int qw = blockIdx.x * 64 + wid * 16;

  short8 qf[4];
#pragma unroll
  for (int kk = 0; kk < 4; ++kk)
    qf[kk] = *(const short8*)(Qp + (long)(qw + c) * HID + h * HD + kk * 32 + g * 8);

  f32x4 o[8] = {};
  f32x4 s[4] = {};
  float m_r[4], l_r[4];
#pragma unroll
  for (int r = 0; r < 4; ++r) { m_r[r] = -__builtin_inff(); l_r[r] = 0.f; }

  const float SL = 0.08838834764831845f * 1.4426950408889634f;  // scale*log2e
  const float ML = 1.4426950408889634f;
  const int kRow = lane >> 4, kSlot = lane & 15;
  const int vRow = lane >> 3, vSlot = lane & 7;
  ushort* Pw = ldsP[wid];

  for (int kv0 = 0; kv0 < S; kv0 += 64) {
#pragma unroll
    for (int i = 0; i < 4; ++i) {
      int ii = wid * 4 + i;
      int rk = ii * 4 + kRow;
      glds16(Kp + (long)(kv0 + rk) * HID + h * HD + ((kSlot ^ (rk & 15)) << 3),
             ldsK + ii * 512);
      int rv = ii * 8 + vRow;
      glds16(Vt + (long)(h * HD + rv) * S + kv0 + ((vSlot ^ (rv & 7)) << 3),
             ldsV + ii * 512);
    }
    __syncthreads();

    // S = Q @ K^T  (acc s[n] zeroed at end of previous iter, far from this use)
#pragma unroll
    for (int n = 0; n < 4; ++n) {
      int row = n * 16 + c;
#pragma unroll
      for (int kk = 0; kk < 4; ++kk) {
        short8 kf = *(const short8*)(ldsK + row * 128 + (((kk * 4 + g) ^ (row & 15)) << 3));
        mfma16(s[n], qf[kk], kf);
      }
    }
    asm volatile("s_nop 7\n\ts_nop 7");

    float tv[4][4];
#pragma unroll
    for (int n = 0; n < 4; ++n)
#pragma unroll
      for (int r = 0; r < 4; ++r) {
        float mv = mask[(long)(qw + g * 4 + r) * S + kv0 + n * 16 + c];
        tv[n][r] = s[n][r] * SL + mv * ML;  // log2 domain
      }
#pragma unroll
    for (int n = 0; n < 4; ++n) s[n] = (f32x4){0.f, 0.f, 0.f, 0.f};

    float al[4];
#pragma unroll
    for (int r = 0; r < 4; ++r) {
      float v = fmaxf(fmaxf(tv[0][r], tv[1][r]), fmaxf(tv[2][r], tv[3][r]));
      v = fmaxf(v, __shfl_xor(v, 1));
      v = fmaxf(v, __shfl_xor(v, 2));
      v = fmaxf(v, __shfl_xor(v, 4));
      v = fmaxf(v, __shfl_xor(v, 8));
      float mnew = fmaxf(m_r[r], v);
      al[r] = __builtin_amdgcn_exp2f(m_r[r] - mnew);
      m_r[r] = mnew;
      l_r[r] *= al[r];
    }
#pragma unroll
    for (int n = 0; n < 8; ++n)
#pragma unroll
      for (int r = 0; r < 4; ++r) o[n][r] *= al[r];

    float ps[4] = {0.f, 0.f, 0.f, 0.f};
#pragma unroll
    for (int n = 0; n < 4; ++n)
#pragma unroll
      for (int r = 0; r < 4; ++r) {
        float p = __builtin_amdgcn_exp2f(tv[n][r] - m_r[r]);
        ps[r] += p;
        int row = g * 4 + r;
        Pw[row * 64 + (((n * 2 + (c >> 3)) ^ (row & 7)) << 3) + (c & 7)] = f2bf(p);
      }
#pragma unroll
    for (int r = 0; r < 4; ++r) {
      float v = ps[r];
      v += __shfl_xor(v, 1); v += __shfl_xor(v, 2);
      v += __shfl_xor(v, 4); v += __shfl_xor(v, 8);
      l_r[r] += v;
    }
    __syncthreads();  // P visible; K-tile reads done

    // O += P @ V
#pragma unroll
    for (int kkp = 0; kkp < 2; ++kkp) {
      short8 pa = *(const short8*)(Pw + c * 64 + (((kkp * 4 + g) ^ (c & 7)) << 3));
#pragma unroll
      for (int n = 0; n < 8; ++n) {
        int row = n * 16 + c;
        short8 vb = *(const short8*)(ldsV + row * 64 + (((kkp * 4 + g) ^ (row & 7)) << 3));
        mfma16(o[n], pa, vb);
      }
    }
    __syncthreads();  // V/P consumed before next stage
  }
  asm volatile("s_nop 7\n\ts_nop 7");
#pragma unroll
  for (int r = 0; r < 4; ++r) {
    float inv = 1.0f / l_r[r];
    long orow = 2L * (qw + g * 4 + r) + blk;
#pragma unroll
    for (int n = 0; n < 8; ++n)
      outf[orow * HID + h * HD + n * 16 + c] = f2bf(o[n][r] * inv);
  }
}

extern "C" void kernel_launch(void* const* d_in, const int* in_sizes, int n_in,
                              void* d_out, int out_size, void* d_ws, size_t ws_size,
                              hipStream_t stream) {
  (void)in_sizes; (void)n_in; (void)out_size; (void)ws_size;
  const float* x_self  = (const float*)d_in[0];
  const float* x_cross = (const float*)d_in[1];
  const float* mask    = (const float*)d_in[2];
  const float* Wq      = (const float*)d_in[3];
  const float* Wk      = (const float*)d_in[4];
  const float* Wv      = (const float*)d_in[5];
  const float* Wo      = (const float*)d_in[6];

  uint8_t* w = (uint8_t*)d_ws;
  const size_t MB8 = (size_t)S * HID * sizeof(ushort);  // 8 MiB
  ushort* xs_bf   = (ushort*)(w + 0 * MB8);  // later reused as Vt
  ushort* xc_bf   = (ushort*)(w + 1 * MB8);  // contiguous with xs_bf -> [xs;xc]
  ushort* Wq_bf   = (ushort*)(w + 2 * MB8);  // later reused as out_flat (16MB)
  ushort* Wk_bf   = (ushort*)(w + 3 * MB8);  // contiguous with Wv_bf -> [Wk|Wv]
  ushort* Wv_bf   = (ushort*)(w + 4 * MB8);
  ushort* Wo_bf   = (ushort*)(w + 5 * MB8);
  ushort* q_self  = (ushort*)(w + 6 * MB8);  // contiguous with q_cross
  ushort* q_cross = (ushort*)(w + 7 * MB8);
  ushort* k_      = (ushort*)(w + 8 * MB8);  // contiguous with v_
  ushort* v_      = (ushort*)(w + 9 * MB8);
  ushort* vt       = xs_bf;   // alias: xs/xc dead after projections
  ushort* out_flat = Wq_bf;   // alias: Wq/Wk bf16 dead after projections

  const int n4 = S * HID / 4;
  dim3 cg((n4 + 255) / 256);
  cast_f32_bf16_k<<<cg, 256, 0, stream>>>(x_self,  xs_bf, n4);
  cast_f32_bf16_k<<<cg, 256, 0, stream>>>(x_cross, xc_bf, n4);
  cast_f32_bf16_k<<<cg, 256, 0, stream>>>(Wq, Wq_bf, n4);
  cast_f32_bf16_k<<<cg, 256, 0, stream>>>(Wk, Wk_bf, n4);
  cast_f32_bf16_k<<<cg, 256, 0, stream>>>(Wv, Wv_bf, n4);
  cast_f32_bf16_k<<<cg, 256, 0, stream>>>(Wo, Wo_bf, n4);

  // [q_self; q_cross] = [xs; xc] @ Wq^T   (M=4096)
  gemm_bt_k<0, 0><<<dim3(16, 32), 256, 0, stream>>>(xs_bf, Wq_bf, q_self, 4096, 2048, 2048);
  // [k | v] = xs @ [Wk | Wv]^T            (N=4096, split outputs)
  gemm_bt_k<0, 1><<<dim3(32, 16), 256, 0, stream>>>(xs_bf, Wk_bf, k_, 2048, 4096, 2048);

  transpose_bf16_k<<<dim3(32, 32), 256, 0, stream>>>(v_, vt);

  attn_k<<<dim3(32, 16, 2), 256, 0, stream>>>(q_self, q_cross, k_, vt, mask, out_flat);

  // out = f32(bf16(out_flat @ Wo^T))      (M=4096)
  gemm_bt_k<1, 0><<<dim3(16, 32), 256, 0, stream>>>(out_flat, Wo_bf, d_out, 4096, 2048, 2048);
}

// Round 2
// 275.060 us; speedup vs baseline: 1.6349x; 1.6349x over previous
//
#include <hip/hip_runtime.h>
#include <hip/hip_bf16.h>
#include <stdint.h>

#define S 2048
#define HID 2048
#define NH 16
#define HD 128

typedef short short8 __attribute__((ext_vector_type(8)));
typedef float f32x4 __attribute__((ext_vector_type(4)));
typedef float f32x16 __attribute__((ext_vector_type(16)));
typedef uint32_t u32;
typedef u32 u32x4 __attribute__((ext_vector_type(4)));

__device__ __forceinline__ ushort f2bf(float x) {
  uint32_t u = __builtin_bit_cast(uint32_t, x);
  if ((u & 0x7fffffffu) > 0x7f800000u) return (ushort)((u >> 16) | 0x40);  // quiet NaN
  uint32_t r = u + 0x7fffu + ((u >> 16) & 1u);                             // RNE
  return (ushort)(r >> 16);
}
__device__ __forceinline__ float bf2f(ushort u) {
  union { uint32_t i; float f; } c; c.i = ((uint32_t)u) << 16; return c.f;
}

// async global->LDS, 16B per lane; LDS dest must be wave-uniform (HW adds lane*16)
__device__ __forceinline__ void glds16(const ushort* g, ushort* l) {
  __builtin_amdgcn_global_load_lds((const __attribute__((address_space(1))) uint32_t*)g,
                                   (__attribute__((address_space(3))) uint32_t*)l, 16, 0, 0);
}

__device__ __forceinline__ void mfma16(f32x4& d, short8 a, short8 b) {
  asm("v_mfma_f32_16x16x32_bf16 %0, %1, %2, %0" : "+v"(d) : "v"(a), "v"(b));
}
// 32x32x16 bf16: A row=lane&31,k=(lane>>5)*8+j; B col=lane&31,same k;
// D col=lane&31, row=(reg&3)+8*(reg>>2)+4*(lane>>5)
__device__ __forceinline__ void mfma32(f32x16& d, short8 a, short8 b) {
  asm("v_mfma_f32_32x32x16_bf16 %0, %1, %2, %0" : "+v"(d) : "v"(a), "v"(b));
}
// a' = concat(a.lo, b.lo); b' = concat(a.hi, b.hi)
__device__ __forceinline__ void plswap(u32& a, u32& b) {
  asm("v_permlane32_swap_b32 %0, %1" : "+v"(a), "+v"(b));
}
__device__ __forceinline__ u32 cvtpk(float lo, float hi) {
  u32 r; asm("v_cvt_pk_bf16_f32 %0, %1, %2" : "=v"(r) : "v"(lo), "v"(hi)); return r;
}

__global__ __launch_bounds__(256) void cast_f32_bf16_k(const float* __restrict__ in,
                                                       ushort* __restrict__ out, int n4) {
  int i = blockIdx.x * 256 + threadIdx.x;
  if (i >= n4) return;
  float4 v = ((const float4*)in)[i];
  ushort4 o;
  o.x = f2bf(v.x); o.y = f2bf(v.y); o.z = f2bf(v.z); o.w = f2bf(v.w);
  ((ushort4*)out)[i] = o;
}

// C[m,n] = sum_k A[m,k]*B[n,k]; A:[M][K] bf16, B:[N][K] bf16.
template <int OUTF32, int NSPLIT>
__global__ __launch_bounds__(256)
void gemm_bt_k(const ushort* __restrict__ A, const ushort* __restrict__ B,
               void* __restrict__ C, int M, int N, int K) {
  __shared__ __align__(16) ushort ldsA[128 * 64];
  __shared__ __align__(16) ushort ldsB[128 * 64];
  const int tid = threadIdx.x, lane = tid & 63, wid = tid >> 6;
  const int g = lane >> 4, c = lane & 15;
  const int wr = wid >> 1, wc = wid & 1;
  const long m0 = (long)blockIdx.y * 128, n0 = (long)blockIdx.x * 128;
  const int srow = lane >> 3, sslot = lane & 7;

  f32x4 acc[4][4] = {};

  for (int k0 = 0; k0 < K; k0 += 64) {
#pragma unroll
    for (int i = 0; i < 4; ++i) {
      int ii = wid * 4 + i;
      int rt = ii * 8 + srow;
      int col = ((sslot ^ (rt & 7)) << 3) + k0;
      glds16(A + (m0 + rt) * (long)K + col, ldsA + ii * 512);
      glds16(B + (n0 + rt) * (long)K + col, ldsB + ii * 512);
    }
    __syncthreads();
#pragma unroll
    for (int kk = 0; kk < 2; ++kk) {
      short8 af[4], bfr[4];
#pragma unroll
      for (int m = 0; m < 4; ++m) {
        int row = wr * 64 + m * 16 + c;
        af[m] = *(const short8*)(ldsA + row * 64 + (((kk * 4 + g) ^ (row & 7)) << 3));
      }
#pragma unroll
      for (int n = 0; n < 4; ++n) {
        int row = wc * 64 + n * 16 + c;
        bfr[n] = *(const short8*)(ldsB + row * 64 + (((kk * 4 + g) ^ (row & 7)) << 3));
      }
#pragma unroll
      for (int m = 0; m < 4; ++m)
#pragma unroll
        for (int n = 0; n < 4; ++n) mfma16(acc[m][n], af[m], bfr[n]);
    }
    __syncthreads();
  }
  asm volatile("s_nop 7\n\ts_nop 7");
#pragma unroll
  for (int m = 0; m < 4; ++m) {
#pragma unroll
    for (int r = 0; r < 4; ++r) {
      long grow = m0 + wr * 64 + m * 16 + g * 4 + r;
#pragma unroll
      for (int n = 0; n < 4; ++n) {
        long gcol = n0 + wc * 64 + n * 16 + c;
        long idx;
        if (NSPLIT) idx = ((gcol >> 11) << 22) + (grow << 11) + (gcol & 2047);
        else        idx = grow * N + gcol;
        float v = acc[m][n][r];
        if (OUTF32) ((float*)C)[idx] = bf2f(f2bf(v));
        else        ((ushort*)C)[idx] = f2bf(v);
      }
    }
  }
}

__global__ __launch_bounds__(256)
void transpose_bf16_k(const ushort* __restrict__ in, ushort* __restrict__ out) {
  __shared__ __align__(16) ushort t[64][72];
  const int tid = threadIdx.x;
  const long bx = (long)blockIdx.x * 64;
  const long by = (long)blockIdx.y * 64;
#pragma unroll
  for (int i = 0; i < 2; ++i) {
    int row = (tid >> 3) + i * 32;
    int col = (tid & 7) * 8;
    *(short8*)(&t[row][col]) = *(const short8*)(in + (by + row) * 2048 + bx + col);
  }
  __syncthreads();
#pragma unroll
  for (int i = 0; i < 2; ++i) {
    int orow = (tid >> 3) + i * 32;
    int ocol = (tid & 7) * 8;
    short8 v;
#pragma unroll
    for (int j = 0; j < 8; ++j) v[j] = (short)t[ocol + j][orow];
    *(short8*)(out + (bx + orow) * 2048 + by + ocol) = v;
  }
}

// Flash attention, 8-warp 32x32 swapped-QK^T structure.
// Grid: (S/256, NH, 2). Block 512 = 8 waves x 32 q-rows.
// Kp: [S][HID] bf16 (head offset applied), Vt: [HID][S] bf16 (pre-transposed).
// Writes out_flat[2*q+blk][h*128+d] bf16.
__global__ __launch_bounds__(512)
void attn2_k(const ushort* __restrict__ Qself, const ushort* __restrict__ Qcross,
             const ushort* __restrict__ Kp, const ushort* __restrict__ Vt,
             const float* __restrict__ mask, ushort* __restrict__ outf) {
  __shared__ __align__(16) ushort ldsK[64 * 128];   // [kv][d] 256B rows, 16 slots, slot^=(row&15)
  __shared__ __align__(16) ushort ldsV[128 * 64];   // [d][kv] 128B rows, 8 slots, slot^=(row&7)
  const int tid = threadIdx.x, lane = tid & 63, wid = tid >> 6;
  const int c31 = lane & 31, hi = lane >> 5;
  const int h = blockIdx.y, blk = blockIdx.z;
  const ushort* Qp = blk ? Qcross : Qself;
  const int qbase = blockIdx.x * 256 + wid * 32;
  const long qme = qbase + c31;  // this lane's q-row (owns P row q=c31)

  // Q fragment: lane holds Q[qme][d = ks*16 + hi*8 + j], ks=0..7
  short8 qf[8];
#pragma unroll
  for (int ks = 0; ks < 8; ++ks)
    qf[ks] = *(const short8*)(Qp + qme * HID + h * HD + ks * 16 + hi * 8);

  f32x16 o[4] = {};   // O[q=(r&3)+8*(r>>2)+4*hi][d = dt*32 + c31]
  float m_r = -__builtin_inff(), l_r = 0.f;

  const float SL = 0.08838834764831845f * 1.4426950408889634f;  // scale*log2e
  const float ML = 1.4426950408889634f;

  const int kRow4 = lane >> 4, kSlot = lane & 15;
  const int vRow8 = lane >> 3, vSlot = lane & 7;

  for (int kv0 = 0; kv0 < S; kv0 += 64) {
    // stage K (16KB) + V (16KB): 16 segs of 1KB each, wave-uniform LDS dests
#pragma unroll
    for (int i = 0; i < 2; ++i) {
      int seg = i * 8 + wid;
      int rk = seg * 4 + kRow4;  // kv row 0..63
      glds16(Kp + (long)(kv0 + rk) * HID + h * HD + ((kSlot ^ (rk & 15)) << 3),
             ldsK + seg * 512);
      int rv = seg * 8 + vRow8;  // d row 0..127
      glds16(Vt + (long)(h * HD + rv) * S + kv0 + ((vSlot ^ (rv & 7)) << 3),
             ldsV + seg * 512);
    }
    __syncthreads();

    // mask values for this lane's P layout: kv = kvb*32 + 8*rg + 4*hi + e
    f32x4 mv[2][4];
#pragma unroll
    for (int kvb = 0; kvb < 2; ++kvb)
#pragma unroll
      for (int rg = 0; rg < 4; ++rg)
        mv[kvb][rg] = *(const f32x4*)(mask + qme * S + kv0 + kvb * 32 + rg * 8 + hi * 4);

    // S^T = K @ Q^T : lane holds P[q=c31][kv = kvb*32 + (r&3)+8*(r>>2)+4*hi]
    f32x16 s0 = {}, s1 = {};
#pragma unroll
    for (int ks = 0; ks < 8; ++ks) {
      int r0 = c31, r1 = 32 + c31;
      short8 kf0 = *(const short8*)(ldsK + r0 * 128 + (((ks * 2 + hi) ^ (r0 & 15)) << 3));
      short8 kf1 = *(const short8*)(ldsK + r1 * 128 + (((ks * 2 + hi) ^ (r1 & 15)) << 3));
      mfma32(s0, kf0, qf[ks]);
      mfma32(s1, kf1, qf[ks]);
    }
    asm volatile("s_nop 7\n\ts_nop 7");

    // log2-domain scores + mask
#pragma unroll
    for (int r = 0; r < 16; ++r) {
      s0[r] = s0[r] * SL + mv[0][r >> 2][r & 3] * ML;
      s1[r] = s1[r] * SL + mv[1][r >> 2][r & 3] * ML;
    }

    // full row max: 31 in-lane fmax + cross-half exchange
    float pmax = s0[0];
#pragma unroll
    for (int r = 1; r < 16; ++r) pmax = fmaxf(pmax, s0[r]);
#pragma unroll
    for (int r = 0; r < 16; ++r) pmax = fmaxf(pmax, s1[r]);
    pmax = fmaxf(pmax, __shfl_xor(pmax, 32));

    // defer-max: rescale only when max grows by > 8 (wave-uniform)
    if (!__all(pmax <= m_r + 8.f)) {
      float mnew = fmaxf(m_r, pmax);
      float alpha = __builtin_amdgcn_exp2f(m_r - mnew);  // exp2(-inf)=0 on tile 0
      m_r = mnew;
      l_r *= alpha;
#pragma unroll
      for (int r = 0; r < 16; ++r) {
        float alf = __shfl(alpha, (r & 3) + 8 * (r >> 2) + 4 * hi);
#pragma unroll
        for (int dt = 0; dt < 4; ++dt) o[dt][r] *= alf;
      }
    }

    // P = exp2(tv - m), row sum
    float lsum = 0.f;
#pragma unroll
    for (int r = 0; r < 16; ++r) {
      s0[r] = __builtin_amdgcn_exp2f(s0[r] - m_r); lsum += s0[r];
      s1[r] = __builtin_amdgcn_exp2f(s1[r] - m_r); lsum += s1[r];
    }
    lsum += __shfl_xor(lsum, 32);
    l_r += lsum;

    // P -> bf16 A-frags: per 16-kv block, 4 cvt_pk + 2 permlane32_swap
    short8 pa[4];
#pragma unroll
    for (int kk = 0; kk < 4; ++kk) {
      const f32x16& sv = (kk < 2) ? s0 : s1;
      const int b = (kk & 1) * 8;
      u32 x0 = cvtpk(sv[b + 0], sv[b + 1]);
      u32 x1 = cvtpk(sv[b + 2], sv[b + 3]);
      u32 y0 = cvtpk(sv[b + 4], sv[b + 5]);
      u32 y1 = cvtpk(sv[b + 6], sv[b + 7]);
      plswap(x0, y0);
      plswap(x1, y1);
      u32x4 t; t[0] = x0; t[1] = x1; t[2] = y0; t[3] = y1;
      pa[kk] = __builtin_bit_cast(short8, t);
    }
    asm volatile("s_nop 3");

    // O += P @ V
#pragma unroll
    for (int dt = 0; dt < 4; ++dt) {
      int row = dt * 32 + c31;
#pragma unroll
      for (int kk = 0; kk < 4; ++kk) {
        short8 vf = *(const short8*)(ldsV + row * 64 + (((kk * 2 + hi) ^ (row & 7)) << 3));
        mfma32(o[dt], pa[kk], vf);
      }
    }
    __syncthreads();
  }

  asm volatile("s_nop 7\n\ts_nop 7");
#pragma unroll
  for (int r = 0; r < 16; ++r) {
    int qr = (r & 3) + 8 * (r >> 2) + 4 * hi;
    float linv = 1.0f / __shfl(l_r, qr);
    long orow = 2L * (qbase + qr) + blk;
#pragma unroll
    for (int dt = 0; dt < 4; ++dt)
      outf[orow * HID + h * HD + dt * 32 + c31] = f2bf(o[dt][r] * linv);
  }
}

extern "C" void kernel_launch(void* const* d_in, const int* in_sizes, int n_in,
                              void* d_out, int out_size, void* d_ws, size_t ws_size,
                              hipStream_t stream) {
  (void)in_sizes; (void)n_in; (void)out_size; (void)ws_size;
  const float* x_self  = (const float*)d_in[0];
  const float* x_cross = (const float*)d_in[1];
  const float* mask    = (const float*)d_in[2];
  const float* Wq      = (const float*)d_in[3];
  const float* Wk      = (const float*)d_in[4];
  const float* Wv      = (const float*)d_in[5];
  const float* Wo      = (const float*)d_in[6];

  uint8_t* w = (uint8_t*)d_ws;
  const size_t MB8 = (size_t)S * HID * sizeof(ushort);  // 8 MiB
  ushort* xs_bf   = (ushort*)(w + 0 * MB8);  // later reused as Vt
  ushort* xc_bf   = (ushort*)(w + 1 * MB8);
  ushort* Wq_bf   = (ushort*)(w + 2 * MB8);  // later reused as out_flat (16MB w/ Wk)
  ushort* Wk_bf   = (ushort*)(w + 3 * MB8);
  ushort* Wv_bf   = (ushort*)(w + 4 * MB8);
  ushort* Wo_bf   = (ushort*)(w + 5 * MB8);
  ushort* q_self  = (ushort*)(w + 6 * MB8);
  ushort* q_cross = (ushort*)(w + 7 * MB8);
  ushort* k_      = (ushort*)(w + 8 * MB8);
  ushort* v_      = (ushort*)(w + 9 * MB8);
  ushort* vt       = xs_bf;
  ushort* out_flat = Wq_bf;

  const int n4 = S * HID / 4;
  dim3 cg((n4 + 255) / 256);
  cast_f32_bf16_k<<<cg, 256, 0, stream>>>(x_self,  xs_bf, n4);
  cast_f32_bf16_k<<<cg, 256, 0, stream>>>(x_cross, xc_bf, n4);
  cast_f32_bf16_k<<<cg, 256, 0, stream>>>(Wq, Wq_bf, n4);
  cast_f32_bf16_k<<<cg, 256, 0, stream>>>(Wk, Wk_bf, n4);
  cast_f32_bf16_k<<<cg, 256, 0, stream>>>(Wv, Wv_bf, n4);
  cast_f32_bf16_k<<<cg, 256, 0, stream>>>(Wo, Wo_bf, n4);

  gemm_bt_k<0, 0><<<dim3(16, 32), 256, 0, stream>>>(xs_bf, Wq_bf, q_self, 4096, 2048, 2048);
  gemm_bt_k<0, 1><<<dim3(32, 16), 256, 0, stream>>>(xs_bf, Wk_bf, k_, 2048, 4096, 2048);

  transpose_bf16_k<<<dim3(32, 32), 256, 0, stream>>>(v_, vt);

  attn2_k<<<dim3(8, 16, 2), 512, 0, stream>>>(q_self, q_cross, k_, vt, mask, out_flat);

  gemm_bt_k<1, 0><<<dim3(16, 32), 256, 0, stream>>>(out_flat, Wo_bf, d_out, 4096, 2048, 2048);
}

// Round 4
// 265.458 us; speedup vs baseline: 1.6940x; 1.0362x over previous
//
#include <hip/hip_runtime.h>
#include <hip/hip_bf16.h>
#include <stdint.h>

#define S 2048
#define HID 2048
#define NH 16
#define HD 128

typedef short short8 __attribute__((ext_vector_type(8)));
typedef float f32x4 __attribute__((ext_vector_type(4)));
typedef float f32x16 __attribute__((ext_vector_type(16)));
typedef uint32_t u32;
typedef u32 u32x4 __attribute__((ext_vector_type(4)));

__device__ __forceinline__ ushort f2bf(float x) {
  uint32_t u = __builtin_bit_cast(uint32_t, x);
  if ((u & 0x7fffffffu) > 0x7f800000u) return (ushort)((u >> 16) | 0x40);  // quiet NaN
  uint32_t r = u + 0x7fffu + ((u >> 16) & 1u);                             // RNE
  return (ushort)(r >> 16);
}
__device__ __forceinline__ float bf2f(ushort u) {
  union { uint32_t i; float f; } c; c.i = ((uint32_t)u) << 16; return c.f;
}

// async global->LDS, 16B per lane; LDS dest must be wave-uniform (HW adds lane*16)
__device__ __forceinline__ void glds16(const ushort* g, ushort* l) {
  __builtin_amdgcn_global_load_lds((const __attribute__((address_space(1))) uint32_t*)g,
                                   (__attribute__((address_space(3))) uint32_t*)l, 16, 0, 0);
}

__device__ __forceinline__ void mfma16(f32x4& d, short8 a, short8 b) {
  asm("v_mfma_f32_16x16x32_bf16 %0, %1, %2, %0" : "+v"(d) : "v"(a), "v"(b));
}
// 32x32x16 bf16: A row=lane&31,k=(lane>>5)*8+j; B col=lane&31,same k;
// D col=lane&31, row=(reg&3)+8*(reg>>2)+4*(lane>>5)
__device__ __forceinline__ void mfma32(f32x16& d, short8 a, short8 b) {
  asm("v_mfma_f32_32x32x16_bf16 %0, %1, %2, %0" : "+v"(d) : "v"(a), "v"(b));
}
// a' = concat(a.lo, b.lo); b' = concat(a.hi, b.hi)
__device__ __forceinline__ void plswap(u32& a, u32& b) {
  asm("v_permlane32_swap_b32 %0, %1" : "+v"(a), "+v"(b));
}
__device__ __forceinline__ u32 cvtpk(float lo, float hi) {
  u32 r; asm("v_cvt_pk_bf16_f32 %0, %1, %2" : "=v"(r) : "v"(lo), "v"(hi)); return r;
}

struct CastArgs { const float* s[6]; ushort* d[6]; };
__global__ __launch_bounds__(256) void cast6_k(CastArgs a) {
  const float* in = a.s[blockIdx.y];
  ushort* out = a.d[blockIdx.y];
  int i = blockIdx.x * 256 + threadIdx.x;
  float4 v = ((const float4*)in)[i];
  ushort4 o;
  o.x = f2bf(v.x); o.y = f2bf(v.y); o.z = f2bf(v.z); o.w = f2bf(v.w);
  ((ushort4*)out)[i] = o;
}

// C[m,n] = sum_k A[m,k]*B[n,k]; A:[M][K] bf16, B:[N][K] bf16.
template <int OUTF32, int NSPLIT>
__global__ __launch_bounds__(256)
void gemm_bt_k(const ushort* __restrict__ A, const ushort* __restrict__ B,
               void* __restrict__ C, int M, int N, int K) {
  __shared__ __align__(16) ushort ldsA[128 * 64];
  __shared__ __align__(16) ushort ldsB[128 * 64];
  const int tid = threadIdx.x, lane = tid & 63, wid = tid >> 6;
  const int g = lane >> 4, c = lane & 15;
  const int wr = wid >> 1, wc = wid & 1;
  const long m0 = (long)blockIdx.y * 128, n0 = (long)blockIdx.x * 128;
  const int srow = lane >> 3, sslot = lane & 7;

  f32x4 acc[4][4] = {};

  for (int k0 = 0; k0 < K; k0 += 64) {
#pragma unroll
    for (int i = 0; i < 4; ++i) {
      int ii = wid * 4 + i;
      int rt = ii * 8 + srow;
      int col = ((sslot ^ (rt & 7)) << 3) + k0;
      glds16(A + (m0 + rt) * (long)K + col, ldsA + ii * 512);
      glds16(B + (n0 + rt) * (long)K + col, ldsB + ii * 512);
    }
    __syncthreads();
#pragma unroll
    for (int kk = 0; kk < 2; ++kk) {
      short8 af[4], bfr[4];
#pragma unroll
      for (int m = 0; m < 4; ++m) {
        int row = wr * 64 + m * 16 + c;
        af[m] = *(const short8*)(ldsA + row * 64 + (((kk * 4 + g) ^ (row & 7)) << 3));
      }
#pragma unroll
      for (int n = 0; n < 4; ++n) {
        int row = wc * 64 + n * 16 + c;
        bfr[n] = *(const short8*)(ldsB + row * 64 + (((kk * 4 + g) ^ (row & 7)) << 3));
      }
#pragma unroll
      for (int m = 0; m < 4; ++m)
#pragma unroll
        for (int n = 0; n < 4; ++n) mfma16(acc[m][n], af[m], bfr[n]);
    }
    __syncthreads();
  }
  asm volatile("s_nop 7\n\ts_nop 7");
#pragma unroll
  for (int m = 0; m < 4; ++m) {
#pragma unroll
    for (int r = 0; r < 4; ++r) {
      long grow = m0 + wr * 64 + m * 16 + g * 4 + r;
#pragma unroll
      for (int n = 0; n < 4; ++n) {
        long gcol = n0 + wc * 64 + n * 16 + c;
        long idx;
        if (NSPLIT) idx = ((gcol >> 11) << 22) + (grow << 11) + (gcol & 2047);
        else        idx = grow * N + gcol;
        float v = acc[m][n][r];
        if (OUTF32) ((float*)C)[idx] = bf2f(f2bf(v));
        else        ((ushort*)C)[idx] = f2bf(v);
      }
    }
  }
}

__global__ __launch_bounds__(256)
void transpose_bf16_k(const ushort* __restrict__ in, ushort* __restrict__ out) {
  __shared__ __align__(16) ushort t[64][72];
  const int tid = threadIdx.x;
  const long bx = (long)blockIdx.x * 64;
  const long by = (long)blockIdx.y * 64;
#pragma unroll
  for (int i = 0; i < 2; ++i) {
    int row = (tid >> 3) + i * 32;
    int col = (tid & 7) * 8;
    *(short8*)(&t[row][col]) = *(const short8*)(in + (by + row) * 2048 + bx + col);
  }
  __syncthreads();
#pragma unroll
  for (int i = 0; i < 2; ++i) {
    int orow = (tid >> 3) + i * 32;
    int ocol = (tid & 7) * 8;
    short8 v;
#pragma unroll
    for (int j = 0; j < 8; ++j) v[j] = (short)t[ocol + j][orow];
    *(short8*)(out + (bx + orow) * 2048 + by + ocol) = v;
  }
}

// Flash attention: 8-wave 32x32 swapped-QK^T, double-buffered K/V, one barrier/tile.
// Softmax numerics = round-2-passing envelope: f32 denominator from pre-rounding p,
// defer-max bound P<=2^8. Grid: (S/256, NH, 2). Block 512 = 8 waves x 32 q-rows.
__global__ __launch_bounds__(512)
void attn3_k(const ushort* __restrict__ Qself, const ushort* __restrict__ Qcross,
             const ushort* __restrict__ Kp, const ushort* __restrict__ Vt,
             const float* __restrict__ mask, ushort* __restrict__ outf) {
  __shared__ __align__(16) ushort ldsK[2 * 64 * 128];   // [buf][kv][d] 256B rows, slot^=(row&15)
  __shared__ __align__(16) ushort ldsV[2 * 128 * 64];   // [buf][d][kv] 128B rows, slot^=(row&7)
  const int tid = threadIdx.x, lane = tid & 63, wid = tid >> 6;
  const int c31 = lane & 31, hi = lane >> 5;
  const int h = blockIdx.y, blk = blockIdx.z;
  const ushort* Qp = blk ? Qcross : Qself;
  const int qbase = blockIdx.x * 256 + wid * 32;
  const long qme = qbase + c31;  // this lane's q-row (owns P row q=c31)

  short8 qf[8];
#pragma unroll
  for (int ks = 0; ks < 8; ++ks)
    qf[ks] = *(const short8*)(Qp + qme * HID + h * HD + ks * 16 + hi * 8);

  f32x16 o[4] = {};   // O[q=(r&3)+8*(r>>2)+4*hi][d = dt*32 + c31]
  float m_r = -__builtin_inff(), l_r = 0.f;

  const float SC  = 0.08838834764831845f;   // 1/sqrt(128)
  const float L2E = 1.4426950408889634f;
  const float THR = 5.545177444479562f;     // 8*ln2 -> P <= 2^8 (round-2 envelope)

  const int kRow4 = lane >> 4, kSlot = lane & 15;
  const int vRow8 = lane >> 3, vSlot = lane & 7;
  const float* mrow = mask + qme * (long)S;

#define STAGE(BO, KV0) do {                                                       \
    _Pragma("unroll")                                                             \
    for (int i_ = 0; i_ < 2; ++i_) {                                              \
      int seg = i_ * 8 + wid;                                                     \
      int rk = seg * 4 + kRow4;                                                   \
      glds16(Kp + (long)((KV0) + rk) * HID + h * HD + ((kSlot ^ (rk & 15)) << 3), \
             ldsK + (BO) * 8192 + seg * 512);                                     \
      int rv = seg * 8 + vRow8;                                                   \
      glds16(Vt + (long)(h * HD + rv) * S + (KV0) + ((vSlot ^ (rv & 7)) << 3),    \
             ldsV + (BO) * 8192 + seg * 512);                                     \
    }                                                                             \
  } while (0)

  STAGE(0, 0);
  __syncthreads();

  for (int t = 0; t < 32; ++t) {
    const int bo = t & 1;
    const ushort* kb = ldsK + bo * 8192;
    const ushort* vb = ldsV + bo * 8192;
    if (t < 31) STAGE(bo ^ 1, (t + 1) * 64);  // prefetch next tile; drains at barrier
    const int kv0 = t * 64;

    // mask for this lane's P layout: kv = kvb*32 + rg*8 + hi*4 + e
    f32x4 mv[2][4];
#pragma unroll
    for (int kvb = 0; kvb < 2; ++kvb)
#pragma unroll
      for (int rg = 0; rg < 4; ++rg)
        mv[kvb][rg] = *(const f32x4*)(mrow + kv0 + kvb * 32 + rg * 8 + hi * 4);

    // S^T = K @ Q^T : lane holds S[q=c31][kv = kvb*32 + (r&3)+8*(r>>2)+4*hi]
    f32x16 s0 = {}, s1 = {};
    __builtin_amdgcn_s_setprio(1);
#pragma unroll
    for (int ks = 0; ks < 8; ++ks) {
      int r0 = c31, r1 = 32 + c31;
      short8 kf0 = *(const short8*)(kb + r0 * 128 + (((ks * 2 + hi) ^ (r0 & 15)) << 3));
      short8 kf1 = *(const short8*)(kb + r1 * 128 + (((ks * 2 + hi) ^ (r1 & 15)) << 3));
      mfma32(s0, kf0, qf[ks]);
      mfma32(s1, kf1, qf[ks]);
    }
    __builtin_amdgcn_s_setprio(0);
    asm volatile("s_nop 7\n\ts_nop 7");

    // natural domain: tv = s*scale + mask  (one FMA per element)
#pragma unroll
    for (int r = 0; r < 16; ++r) {
      s0[r] = __builtin_fmaf(s0[r], SC, mv[0][r >> 2][r & 3]);
      s1[r] = __builtin_fmaf(s1[r], SC, mv[1][r >> 2][r & 3]);
    }

    float pmax = s0[0];
#pragma unroll
    for (int r = 1; r < 16; ++r) pmax = fmaxf(pmax, s0[r]);
#pragma unroll
    for (int r = 0; r < 16; ++r) pmax = fmaxf(pmax, s1[r]);
    pmax = fmaxf(pmax, __shfl_xor(pmax, 32));

    // defer-max: rescale O and l only when max grows by > THR (wave-uniform)
    if (!__all(pmax <= m_r + THR)) {
      float mnew = fmaxf(m_r, pmax);
      float alpha = __builtin_amdgcn_exp2f((m_r - mnew) * L2E);  // 0 on first tile
      m_r = mnew;
      l_r *= alpha;
#pragma unroll
      for (int r = 0; r < 16; ++r) {
        float alf = __shfl(alpha, (r & 3) + 8 * (r >> 2) + 4 * hi);
#pragma unroll
        for (int dt = 0; dt < 4; ++dt) o[dt][r] *= alf;
      }
    }

    // P = exp(tv - m) = exp2(fma(tv, L2E, -m*L2E)); f32 row-sum (matches ref denom)
    const float nm = -m_r * L2E;
    float lsum = 0.f;
#pragma unroll
    for (int r = 0; r < 16; ++r) {
      s0[r] = __builtin_amdgcn_exp2f(__builtin_fmaf(s0[r], L2E, nm)); lsum += s0[r];
      s1[r] = __builtin_amdgcn_exp2f(__builtin_fmaf(s1[r], L2E, nm)); lsum += s1[r];
    }
    lsum += __shfl_xor(lsum, 32);
    l_r += lsum;

    // P -> bf16 A-frags: per 16-kv block, 4 cvt_pk + 2 permlane32_swap
    short8 pa[4];
#pragma unroll
    for (int kk = 0; kk < 4; ++kk) {
      const f32x16& sv = (kk < 2) ? s0 : s1;
      const int b = (kk & 1) * 8;
      u32 x0 = cvtpk(sv[b + 0], sv[b + 1]);
      u32 x1 = cvtpk(sv[b + 2], sv[b + 3]);
      u32 y0 = cvtpk(sv[b + 4], sv[b + 5]);
      u32 y1 = cvtpk(sv[b + 6], sv[b + 7]);
      plswap(x0, y0);
      plswap(x1, y1);
      u32x4 tt; tt[0] = x0; tt[1] = x1; tt[2] = y0; tt[3] = y1;
      pa[kk] = __builtin_bit_cast(short8, tt);
    }
    asm volatile("s_nop 3");

    // O += P @ V
    __builtin_amdgcn_s_setprio(1);
#pragma unroll
    for (int dt = 0; dt < 4; ++dt) {
      int row = dt * 32 + c31;
#pragma unroll
      for (int kk = 0; kk < 4; ++kk) {
        short8 vf = *(const short8*)(vb + row * 64 + (((kk * 2 + hi) ^ (row & 7)) << 3));
        mfma32(o[dt], pa[kk], vf);
      }
    }
    __builtin_amdgcn_s_setprio(0);

    __syncthreads();  // next-tile stage drained + all waves done reading this buf
  }
#undef STAGE

  asm volatile("s_nop 7\n\ts_nop 7");
#pragma unroll
  for (int r = 0; r < 16; ++r) {
    int qr = (r & 3) + 8 * (r >> 2) + 4 * hi;
    float linv = 1.0f / __shfl(l_r, qr);
    long orow = 2L * (qbase + qr) + blk;
#pragma unroll
    for (int dt = 0; dt < 4; ++dt)
      outf[orow * HID + h * HD + dt * 32 + c31] = f2bf(o[dt][r] * linv);
  }
}

extern "C" void kernel_launch(void* const* d_in, const int* in_sizes, int n_in,
                              void* d_out, int out_size, void* d_ws, size_t ws_size,
                              hipStream_t stream) {
  (void)in_sizes; (void)n_in; (void)out_size; (void)ws_size;
  const float* x_self  = (const float*)d_in[0];
  const float* x_cross = (const float*)d_in[1];
  const float* mask    = (const float*)d_in[2];
  const float* Wq      = (const float*)d_in[3];
  const float* Wk      = (const float*)d_in[4];
  const float* Wv      = (const float*)d_in[5];
  const float* Wo      = (const float*)d_in[6];

  uint8_t* w = (uint8_t*)d_ws;
  const size_t MB8 = (size_t)S * HID * sizeof(ushort);  // 8 MiB
  ushort* xs_bf   = (ushort*)(w + 0 * MB8);  // later reused as Vt
  ushort* xc_bf   = (ushort*)(w + 1 * MB8);
  ushort* Wq_bf   = (ushort*)(w + 2 * MB8);  // later reused as out_flat (16MB w/ Wk)
  ushort* Wk_bf   = (ushort*)(w + 3 * MB8);
  ushort* Wv_bf   = (ushort*)(w + 4 * MB8);
  ushort* Wo_bf   = (ushort*)(w + 5 * MB8);
  ushort* q_self  = (ushort*)(w + 6 * MB8);
  ushort* q_cross = (ushort*)(w + 7 * MB8);
  ushort* k_      = (ushort*)(w + 8 * MB8);
  ushort* v_      = (ushort*)(w + 9 * MB8);
  ushort* vt       = xs_bf;
  ushort* out_flat = Wq_bf;

  CastArgs ca;
  ca.s[0] = x_self;  ca.d[0] = xs_bf;
  ca.s[1] = x_cross; ca.d[1] = xc_bf;
  ca.s[2] = Wq;      ca.d[2] = Wq_bf;
  ca.s[3] = Wk;      ca.d[3] = Wk_bf;
  ca.s[4] = Wv;      ca.d[4] = Wv_bf;
  ca.s[5] = Wo;      ca.d[5] = Wo_bf;
  cast6_k<<<dim3(4096, 6), 256, 0, stream>>>(ca);

  gemm_bt_k<0, 0><<<dim3(16, 32), 256, 0, stream>>>(xs_bf, Wq_bf, q_self, 4096, 2048, 2048);
  gemm_bt_k<0, 1><<<dim3(32, 16), 256, 0, stream>>>(xs_bf, Wk_bf, k_, 2048, 4096, 2048);

  transpose_bf16_k<<<dim3(32, 32), 256, 0, stream>>>(v_, vt);

  attn3_k<<<dim3(8, 16, 2), 512, 0, stream>>>(q_self, q_cross, k_, vt, mask, out_flat);

  gemm_bt_k<1, 0><<<dim3(16, 32), 256, 0, stream>>>(out_flat, Wo_bf, d_out, 4096, 2048, 2048);
}

// Round 6
// 256.734 us; speedup vs baseline: 1.7516x; 1.0340x over previous
//
#include <hip/hip_runtime.h>
#include <hip/hip_bf16.h>
#include <stdint.h>

#define S 2048
#define HID 2048
#define NH 16
#define HD 128

typedef short short8 __attribute__((ext_vector_type(8)));
typedef float f32x4 __attribute__((ext_vector_type(4)));
typedef float f32x16 __attribute__((ext_vector_type(16)));
typedef uint32_t u32;
typedef u32 u32x4 __attribute__((ext_vector_type(4)));

__device__ __forceinline__ ushort f2bf(float x) {
  uint32_t u = __builtin_bit_cast(uint32_t, x);
  if ((u & 0x7fffffffu) > 0x7f800000u) return (ushort)((u >> 16) | 0x40);  // quiet NaN
  uint32_t r = u + 0x7fffu + ((u >> 16) & 1u);                             // RNE
  return (ushort)(r >> 16);
}
__device__ __forceinline__ float bf2f(ushort u) {
  union { uint32_t i; float f; } c; c.i = ((uint32_t)u) << 16; return c.f;
}

// async global->LDS, 16B per lane; LDS dest must be wave-uniform (HW adds lane*16)
__device__ __forceinline__ void glds16(const ushort* g, ushort* l) {
  __builtin_amdgcn_global_load_lds((const __attribute__((address_space(1))) uint32_t*)g,
                                   (__attribute__((address_space(3))) uint32_t*)l, 16, 0, 0);
}

// MFMA via inline asm: compiler cannot see these are MFMAs, so it will NOT pad
// the MFMA->VALU RAW hazard (no HW interlock). All asm here is volatile (keeps
// relative order of volatile ops) and every MFMA->VALU boundary is fenced with
// MFMA_FENCE(): one un-splittable 24-cycle s_nop block + sched_barrier(0) so
// dependent VALU reads cannot be scheduled into the hazard window (rule #18).
__device__ __forceinline__ void mfma16(f32x4& d, short8 a, short8 b) {
  asm volatile("v_mfma_f32_16x16x32_bf16 %0, %1, %2, %0" : "+v"(d) : "v"(a), "v"(b));
}
// 32x32x16 bf16: A row=lane&31,k=(lane>>5)*8+j; B col=lane&31,same k;
// D col=lane&31, row=(reg&3)+8*(reg>>2)+4*(lane>>5)
__device__ __forceinline__ void mfma32(f32x16& d, short8 a, short8 b) {
  asm volatile("v_mfma_f32_32x32x16_bf16 %0, %1, %2, %0" : "+v"(d) : "v"(a), "v"(b));
}
#define MFMA_FENCE() do {                              \
    asm volatile("s_nop 7\n\ts_nop 7\n\ts_nop 7");     \
    __builtin_amdgcn_sched_barrier(0);                 \
  } while (0)
// a' = concat(a.lo, b.lo); b' = concat(a.hi, b.hi)
__device__ __forceinline__ void plswap(u32& a, u32& b) {
  asm volatile("v_permlane32_swap_b32 %0, %1" : "+v"(a), "+v"(b));
}
__device__ __forceinline__ u32 cvtpk(float lo, float hi) {
  u32 r; asm volatile("v_cvt_pk_bf16_f32 %0, %1, %2" : "=v"(r) : "v"(lo), "v"(hi)); return r;
}

struct CastArgs { const float* s[6]; ushort* d[6]; };
__global__ __launch_bounds__(256) void cast6_k(CastArgs a) {
  const float* in = a.s[blockIdx.y];
  ushort* out = a.d[blockIdx.y];
  int i = blockIdx.x * 256 + threadIdx.x;
  float4 v = ((const float4*)in)[i];
  ushort4 o;
  o.x = f2bf(v.x); o.y = f2bf(v.y); o.z = f2bf(v.z); o.w = f2bf(v.w);
  ((ushort4*)out)[i] = o;
}

// C[m,n] = sum_k A[m,k]*B[n,k]; A:[M][K] bf16, B:[N][K] bf16.
template <int OUTF32, int NSPLIT>
__global__ __launch_bounds__(256)
void gemm_bt_k(const ushort* __restrict__ A, const ushort* __restrict__ B,
               void* __restrict__ C, int M, int N, int K) {
  __shared__ __align__(16) ushort ldsA[128 * 64];
  __shared__ __align__(16) ushort ldsB[128 * 64];
  const int tid = threadIdx.x, lane = tid & 63, wid = tid >> 6;
  const int g = lane >> 4, c = lane & 15;
  const int wr = wid >> 1, wc = wid & 1;
  const long m0 = (long)blockIdx.y * 128, n0 = (long)blockIdx.x * 128;
  const int srow = lane >> 3, sslot = lane & 7;

  f32x4 acc[4][4] = {};

  for (int k0 = 0; k0 < K; k0 += 64) {
#pragma unroll
    for (int i = 0; i < 4; ++i) {
      int ii = wid * 4 + i;
      int rt = ii * 8 + srow;
      int col = ((sslot ^ (rt & 7)) << 3) + k0;
      glds16(A + (m0 + rt) * (long)K + col, ldsA + ii * 512);
      glds16(B + (n0 + rt) * (long)K + col, ldsB + ii * 512);
    }
    __syncthreads();
#pragma unroll
    for (int kk = 0; kk < 2; ++kk) {
      short8 af[4], bfr[4];
#pragma unroll
      for (int m = 0; m < 4; ++m) {
        int row = wr * 64 + m * 16 + c;
        af[m] = *(const short8*)(ldsA + row * 64 + (((kk * 4 + g) ^ (row & 7)) << 3));
      }
#pragma unroll
      for (int n = 0; n < 4; ++n) {
        int row = wc * 64 + n * 16 + c;
        bfr[n] = *(const short8*)(ldsB + row * 64 + (((kk * 4 + g) ^ (row & 7)) << 3));
      }
#pragma unroll
      for (int m = 0; m < 4; ++m)
#pragma unroll
        for (int n = 0; n < 4; ++n) mfma16(acc[m][n], af[m], bfr[n]);
    }
    __syncthreads();
  }
  MFMA_FENCE();
#pragma unroll
  for (int m = 0; m < 4; ++m) {
#pragma unroll
    for (int r = 0; r < 4; ++r) {
      long grow = m0 + wr * 64 + m * 16 + g * 4 + r;
#pragma unroll
      for (int n = 0; n < 4; ++n) {
        long gcol = n0 + wc * 64 + n * 16 + c;
        long idx;
        if (NSPLIT) idx = ((gcol >> 11) << 22) + (grow << 11) + (gcol & 2047);
        else        idx = grow * N + gcol;
        float v = acc[m][n][r];
        if (OUTF32) ((float*)C)[idx] = bf2f(f2bf(v));
        else        ((ushort*)C)[idx] = f2bf(v);
      }
    }
  }
}

__global__ __launch_bounds__(256)
void transpose_bf16_k(const ushort* __restrict__ in, ushort* __restrict__ out) {
  __shared__ __align__(16) ushort t[64][72];
  const int tid = threadIdx.x;
  const long bx = (long)blockIdx.x * 64;
  const long by = (long)blockIdx.y * 64;
#pragma unroll
  for (int i = 0; i < 2; ++i) {
    int row = (tid >> 3) + i * 32;
    int col = (tid & 7) * 8;
    *(short8*)(&t[row][col]) = *(const short8*)(in + (by + row) * 2048 + bx + col);
  }
  __syncthreads();
#pragma unroll
  for (int i = 0; i < 2; ++i) {
    int orow = (tid >> 3) + i * 32;
    int ocol = (tid & 7) * 8;
    short8 v;
#pragma unroll
    for (int j = 0; j < 8; ++j) v[j] = (short)t[ocol + j][orow];
    *(short8*)(out + (bx + orow) * 2048 + by + ocol) = v;
  }
}

// Flash attention: 4-wave blocks (q-tile 128), 2 blocks/CU, XCD-aware head mapping.
// Swapped QK^T, double-buffered K/V, one barrier/tile, tree reductions,
// hazard-fenced MFMA->VALU boundaries. Grid: 512. Block 256 = 4 waves x 32 q-rows.
__global__ __launch_bounds__(256)
void attn4_k(const ushort* __restrict__ Qself, const ushort* __restrict__ Qcross,
             const ushort* __restrict__ Kp, const ushort* __restrict__ Vt,
             const float* __restrict__ mask, ushort* __restrict__ outf) {
  __shared__ __align__(16) ushort ldsK[2 * 64 * 128];   // [buf][kv][d] 256B rows, slot^=(row&15)
  __shared__ __align__(16) ushort ldsV[2 * 128 * 64];   // [buf][d][kv] 128B rows, slot^=(row&7)
  const int tid = threadIdx.x, lane = tid & 63, wid = tid >> 6;
  const int c31 = lane & 31, hi = lane >> 5;

  // XCD-aware decode: head h lives on XCD h%8; all blocks sharing head-pair
  // {h, h+8} K/V land on one XCD's L2.
  const int b = blockIdx.x;
  const int xcd = b & 7, j = b >> 3;
  const int h = xcd + 8 * (j & 1);
  const int blk = (j >> 1) & 1;       // 0=self 1=cross
  const int qt = j >> 2;              // 0..15, q-tile of 128 rows

  const ushort* Qp = blk ? Qcross : Qself;
  const int qbase = qt * 128 + wid * 32;
  const long qme = qbase + c31;  // this lane's q-row (owns P row q=c31)

  short8 qf[8];
#pragma unroll
  for (int ks = 0; ks < 8; ++ks)
    qf[ks] = *(const short8*)(Qp + qme * HID + h * HD + ks * 16 + hi * 8);

  f32x16 o[4] = {};   // O[q=(r&3)+8*(r>>2)+4*hi][d = dt*32 + c31]
  float m_r = -__builtin_inff(), l_r = 0.f;

  const float SC  = 0.08838834764831845f;   // 1/sqrt(128)
  const float L2E = 1.4426950408889634f;
  const float THR = 5.545177444479562f;     // 8*ln2 -> P <= 2^8

  const int kRow4 = lane >> 4, kSlot = lane & 15;
  const int vRow8 = lane >> 3, vSlot = lane & 7;
  const float* mrow = mask + qme * (long)S;

#define STAGE(BO, KV0) do {                                                       \
    _Pragma("unroll")                                                             \
    for (int i_ = 0; i_ < 4; ++i_) {                                              \
      int seg = i_ * 4 + wid;                                                     \
      int rk = seg * 4 + kRow4;                                                   \
      glds16(Kp + (long)((KV0) + rk) * HID + h * HD + ((kSlot ^ (rk & 15)) << 3), \
             ldsK + (BO) * 8192 + seg * 512);                                     \
      int rv = seg * 8 + vRow8;                                                   \
      glds16(Vt + (long)(h * HD + rv) * S + (KV0) + ((vSlot ^ (rv & 7)) << 3),    \
             ldsV + (BO) * 8192 + seg * 512);                                     \
    }                                                                             \
  } while (0)

  STAGE(0, 0);
  __syncthreads();

  for (int t = 0; t < 32; ++t) {
    const int bo = t & 1;
    const ushort* kb = ldsK + bo * 8192;
    const ushort* vb = ldsV + bo * 8192;
    if (t < 31) STAGE(bo ^ 1, (t + 1) * 64);  // prefetch next tile; drains at barrier
    const int kv0 = t * 64;

    // mask for this lane's P layout: kv = kvb*32 + rg*8 + hi*4 + e
    f32x4 mv[2][4];
#pragma unroll
    for (int kvb = 0; kvb < 2; ++kvb)
#pragma unroll
      for (int rg = 0; rg < 4; ++rg)
        mv[kvb][rg] = *(const f32x4*)(mrow + kv0 + kvb * 32 + rg * 8 + hi * 4);

    // S^T = K @ Q^T : lane holds S[q=c31][kv = kvb*32 + (r&3)+8*(r>>2)+4*hi]
    f32x16 s0 = {}, s1 = {};
    __builtin_amdgcn_s_setprio(1);
#pragma unroll
    for (int ks = 0; ks < 8; ++ks) {
      int r0 = c31, r1 = 32 + c31;
      short8 kf0 = *(const short8*)(kb + r0 * 128 + (((ks * 2 + hi) ^ (r0 & 15)) << 3));
      short8 kf1 = *(const short8*)(kb + r1 * 128 + (((ks * 2 + hi) ^ (r1 & 15)) << 3));
      mfma32(s0, kf0, qf[ks]);
      mfma32(s1, kf1, qf[ks]);
    }
    __builtin_amdgcn_s_setprio(0);
    MFMA_FENCE();  // s0/s1 read by VALU below; s1 written by the LAST mfma

    // natural domain: tv = s*scale + mask  (one FMA per element)
#pragma unroll
    for (int r = 0; r < 16; ++r) {
      s0[r] = __builtin_fmaf(s0[r], SC, mv[0][r >> 2][r & 3]);
      s1[r] = __builtin_fmaf(s1[r], SC, mv[1][r >> 2][r & 3]);
    }

    // row max: pairwise tree (depth 5) + cross-half exchange
    float mx[16];
#pragma unroll
    for (int r = 0; r < 16; ++r) mx[r] = fmaxf(s0[r], s1[r]);
#pragma unroll
    for (int st = 8; st >= 1; st >>= 1)
#pragma unroll
      for (int i = 0; i < 8; ++i)
        if (i < st) mx[i] = fmaxf(mx[i], mx[i + st]);
    float pmax = fmaxf(mx[0], __shfl_xor(mx[0], 32));

    // defer-max: rescale O and l only when max grows by > THR (wave-uniform)
    if (!__all(pmax <= m_r + THR)) {
      float mnew = fmaxf(m_r, pmax);
      float alpha = __builtin_amdgcn_exp2f((m_r - mnew) * L2E);  // 0 on first tile
      m_r = mnew;
      l_r *= alpha;
#pragma unroll
      for (int r = 0; r < 16; ++r) {
        float alf = __shfl(alpha, (r & 3) + 8 * (r >> 2) + 4 * hi);
#pragma unroll
        for (int dt = 0; dt < 4; ++dt) o[dt][r] *= alf;
      }
    }

    // P = exp(tv - m) = exp2(fma(tv, L2E, -m*L2E)); f32 row-sum via tree
    const float nm = -m_r * L2E;
#pragma unroll
    for (int r = 0; r < 16; ++r) {
      s0[r] = __builtin_amdgcn_exp2f(__builtin_fmaf(s0[r], L2E, nm));
      s1[r] = __builtin_amdgcn_exp2f(__builtin_fmaf(s1[r], L2E, nm));
    }
    float sm[16];
#pragma unroll
    for (int r = 0; r < 16; ++r) sm[r] = s0[r] + s1[r];
#pragma unroll
    for (int st = 8; st >= 1; st >>= 1)
#pragma unroll
      for (int i = 0; i < 8; ++i)
        if (i < st) sm[i] += sm[i + st];
    l_r += sm[0] + __shfl_xor(sm[0], 32);

    // P -> bf16 A-frags: per 16-kv block, 4 cvt_pk + 2 permlane32_swap
    short8 pa[4];
#pragma unroll
    for (int kk = 0; kk < 4; ++kk) {
      const f32x16& sv = (kk < 2) ? s0 : s1;
      const int bq = (kk & 1) * 8;
      u32 x0 = cvtpk(sv[bq + 0], sv[bq + 1]);
      u32 x1 = cvtpk(sv[bq + 2], sv[bq + 3]);
      u32 y0 = cvtpk(sv[bq + 4], sv[bq + 5]);
      u32 y1 = cvtpk(sv[bq + 6], sv[bq + 7]);
      plswap(x0, y0);
      plswap(x1, y1);
      u32x4 tt; tt[0] = x0; tt[1] = x1; tt[2] = y0; tt[3] = y1;
      pa[kk] = __builtin_bit_cast(short8, tt);
    }
    // VALU(permlane) -> MFMA SrcA hazard padding
    asm volatile("s_nop 1");
    __builtin_amdgcn_sched_barrier(0);

    // O += P @ V
    __builtin_amdgcn_s_setprio(1);
#pragma unroll
    for (int dt = 0; dt < 4; ++dt) {
      int row = dt * 32 + c31;
#pragma unroll
      for (int kk = 0; kk < 4; ++kk) {
        short8 vf = *(const short8*)(vb + row * 64 + (((kk * 2 + hi) ^ (row & 7)) << 3));
        mfma32(o[dt], pa[kk], vf);
      }
    }
    __builtin_amdgcn_s_setprio(0);

    __syncthreads();  // next-tile stage drained + all waves done reading this buf
  }
#undef STAGE

  MFMA_FENCE();  // o[] read by VALU epilogue; o[3] written by the LAST mfma
#pragma unroll
  for (int r = 0; r < 16; ++r) {
    int qr = (r & 3) + 8 * (r >> 2) + 4 * hi;
    float linv = 1.0f / __shfl(l_r, qr);
    long orow = 2L * (qbase + qr) + blk;
#pragma unroll
    for (int dt = 0; dt < 4; ++dt)
      outf[orow * HID + h * HD + dt * 32 + c31] = f2bf(o[dt][r] * linv);
  }
}

extern "C" void kernel_launch(void* const* d_in, const int* in_sizes, int n_in,
                              void* d_out, int out_size, void* d_ws, size_t ws_size,
                              hipStream_t stream) {
  (void)in_sizes; (void)n_in; (void)out_size; (void)ws_size;
  const float* x_self  = (const float*)d_in[0];
  const float* x_cross = (const float*)d_in[1];
  const float* mask    = (const float*)d_in[2];
  const float* Wq      = (const float*)d_in[3];
  const float* Wk      = (const float*)d_in[4];
  const float* Wv      = (const float*)d_in[5];
  const float* Wo      = (const float*)d_in[6];

  uint8_t* w = (uint8_t*)d_ws;
  const size_t MB8 = (size_t)S * HID * sizeof(ushort);  // 8 MiB
  ushort* xs_bf   = (ushort*)(w + 0 * MB8);  // later reused as Vt
  ushort* xc_bf   = (ushort*)(w + 1 * MB8);
  ushort* Wq_bf   = (ushort*)(w + 2 * MB8);  // later reused as out_flat (16MB w/ Wk)
  ushort* Wk_bf   = (ushort*)(w + 3 * MB8);
  ushort* Wv_bf   = (ushort*)(w + 4 * MB8);
  ushort* Wo_bf   = (ushort*)(w + 5 * MB8);
  ushort* q_self  = (ushort*)(w + 6 * MB8);
  ushort* q_cross = (ushort*)(w + 7 * MB8);
  ushort* k_      = (ushort*)(w + 8 * MB8);
  ushort* v_      = (ushort*)(w + 9 * MB8);
  ushort* vt       = xs_bf;
  ushort* out_flat = Wq_bf;

  CastArgs ca;
  ca.s[0] = x_self;  ca.d[0] = xs_bf;
  ca.s[1] = x_cross; ca.d[1] = xc_bf;
  ca.s[2] = Wq;      ca.d[2] = Wq_bf;
  ca.s[3] = Wk;      ca.d[3] = Wk_bf;
  ca.s[4] = Wv;      ca.d[4] = Wv_bf;
  ca.s[5] = Wo;      ca.d[5] = Wo_bf;
  cast6_k<<<dim3(4096, 6), 256, 0, stream>>>(ca);

  gemm_bt_k<0, 0><<<dim3(16, 32), 256, 0, stream>>>(xs_bf, Wq_bf, q_self, 4096, 2048, 2048);
  gemm_bt_k<0, 1><<<dim3(32, 16), 256, 0, stream>>>(xs_bf, Wk_bf, k_, 2048, 4096, 2048);

  transpose_bf16_k<<<dim3(32, 32), 256, 0, stream>>>(v_, vt);

  attn4_k<<<dim3(512), 256, 0, stream>>>(q_self, q_cross, k_, vt, mask, out_flat);

  gemm_bt_k<1, 0><<<dim3(16, 32), 256, 0, stream>>>(out_flat, Wo_bf, d_out, 4096, 2048, 2048);
}

// Round 7
// 253.384 us; speedup vs baseline: 1.7748x; 1.0132x over previous
//
#include <hip/hip_runtime.h>
#include <hip/hip_bf16.h>
#include <stdint.h>

#define S 2048
#define HID 2048
#define NH 16
#define HD 128

typedef short short8 __attribute__((ext_vector_type(8)));
typedef float f32x4 __attribute__((ext_vector_type(4)));
typedef float f32x16 __attribute__((ext_vector_type(16)));
typedef uint32_t u32;
typedef u32 u32x4 __attribute__((ext_vector_type(4)));

__device__ __forceinline__ ushort f2bf(float x) {
  uint32_t u = __builtin_bit_cast(uint32_t, x);
  if ((u & 0x7fffffffu) > 0x7f800000u) return (ushort)((u >> 16) | 0x40);  // quiet NaN
  uint32_t r = u + 0x7fffu + ((u >> 16) & 1u);                             // RNE
  return (ushort)(r >> 16);
}
__device__ __forceinline__ float bf2f(ushort u) {
  union { uint32_t i; float f; } c; c.i = ((uint32_t)u) << 16; return c.f;
}

// async global->LDS, 16B per lane; LDS dest must be wave-uniform (HW adds lane*16)
__device__ __forceinline__ void glds16(const ushort* g, ushort* l) {
  __builtin_amdgcn_global_load_lds((const __attribute__((address_space(1))) uint32_t*)g,
                                   (__attribute__((address_space(3))) uint32_t*)l, 16, 0, 0);
}

// MFMA via inline asm: compiler cannot see these are MFMAs, so it will NOT pad
// the MFMA->VALU RAW hazard (no HW interlock). All asm volatile; every
// MFMA->VALU boundary fenced with MFMA_FENCE() (s_nop block + sched_barrier).
__device__ __forceinline__ void mfma16(f32x4& d, short8 a, short8 b) {
  asm volatile("v_mfma_f32_16x16x32_bf16 %0, %1, %2, %0" : "+v"(d) : "v"(a), "v"(b));
}
// 32x32x16 bf16: A row=lane&31,k=(lane>>5)*8+j; B col=lane&31,same k;
// D col=lane&31, row=(reg&3)+8*(reg>>2)+4*(lane>>5)
__device__ __forceinline__ void mfma32(f32x16& d, short8 a, short8 b) {
  asm volatile("v_mfma_f32_32x32x16_bf16 %0, %1, %2, %0" : "+v"(d) : "v"(a), "v"(b));
}
#define MFMA_FENCE() do {                              \
    asm volatile("s_nop 7\n\ts_nop 7\n\ts_nop 7");     \
    __builtin_amdgcn_sched_barrier(0);                 \
  } while (0)
// a' = concat(a.lo, b.lo); b' = concat(a.hi, b.hi)
__device__ __forceinline__ void plswap(u32& a, u32& b) {
  asm volatile("v_permlane32_swap_b32 %0, %1" : "+v"(a), "+v"(b));
}
__device__ __forceinline__ u32 cvtpk(float lo, float hi) {
  u32 r; asm volatile("v_cvt_pk_bf16_f32 %0, %1, %2" : "=v"(r) : "v"(lo), "v"(hi)); return r;
}

struct CastArgs { const float* s[6]; ushort* d[6]; };
__global__ __launch_bounds__(256) void cast6_k(CastArgs a) {
  const float* in = a.s[blockIdx.y];
  ushort* out = a.d[blockIdx.y];
  int i = blockIdx.x * 256 + threadIdx.x;
  float4 v = ((const float4*)in)[i];
  ushort4 o;
  o.x = f2bf(v.x); o.y = f2bf(v.y); o.z = f2bf(v.z); o.w = f2bf(v.w);
  ((ushort4*)out)[i] = o;
}

// C[m,n] = sum_k A[m,k]*B[n,k]; A:[M][K] bf16, B:[N][K] bf16.
template <int OUTF32, int NSPLIT>
__global__ __launch_bounds__(256)
void gemm_bt_k(const ushort* __restrict__ A, const ushort* __restrict__ B,
               void* __restrict__ C, int M, int N, int K) {
  __shared__ __align__(16) ushort ldsA[128 * 64];
  __shared__ __align__(16) ushort ldsB[128 * 64];
  const int tid = threadIdx.x, lane = tid & 63, wid = tid >> 6;
  const int g = lane >> 4, c = lane & 15;
  const int wr = wid >> 1, wc = wid & 1;
  const long m0 = (long)blockIdx.y * 128, n0 = (long)blockIdx.x * 128;
  const int srow = lane >> 3, sslot = lane & 7;

  f32x4 acc[4][4] = {};

  for (int k0 = 0; k0 < K; k0 += 64) {
#pragma unroll
    for (int i = 0; i < 4; ++i) {
      int ii = wid * 4 + i;
      int rt = ii * 8 + srow;
      int col = ((sslot ^ (rt & 7)) << 3) + k0;
      glds16(A + (m0 + rt) * (long)K + col, ldsA + ii * 512);
      glds16(B + (n0 + rt) * (long)K + col, ldsB + ii * 512);
    }
    __syncthreads();
#pragma unroll
    for (int kk = 0; kk < 2; ++kk) {
      short8 af[4], bfr[4];
#pragma unroll
      for (int m = 0; m < 4; ++m) {
        int row = wr * 64 + m * 16 + c;
        af[m] = *(const short8*)(ldsA + row * 64 + (((kk * 4 + g) ^ (row & 7)) << 3));
      }
#pragma unroll
      for (int n = 0; n < 4; ++n) {
        int row = wc * 64 + n * 16 + c;
        bfr[n] = *(const short8*)(ldsB + row * 64 + (((kk * 4 + g) ^ (row & 7)) << 3));
      }
#pragma unroll
      for (int m = 0; m < 4; ++m)
#pragma unroll
        for (int n = 0; n < 4; ++n) mfma16(acc[m][n], af[m], bfr[n]);
    }
    __syncthreads();
  }
  MFMA_FENCE();
#pragma unroll
  for (int m = 0; m < 4; ++m) {
#pragma unroll
    for (int r = 0; r < 4; ++r) {
      long grow = m0 + wr * 64 + m * 16 + g * 4 + r;
#pragma unroll
      for (int n = 0; n < 4; ++n) {
        long gcol = n0 + wc * 64 + n * 16 + c;
        long idx;
        if (NSPLIT) idx = ((gcol >> 11) << 22) + (grow << 11) + (gcol & 2047);
        else        idx = grow * N + gcol;
        float v = acc[m][n][r];
        if (OUTF32) ((float*)C)[idx] = bf2f(f2bf(v));
        else        ((ushort*)C)[idx] = f2bf(v);
      }
    }
  }
}

__global__ __launch_bounds__(256)
void transpose_bf16_k(const ushort* __restrict__ in, ushort* __restrict__ out) {
  __shared__ __align__(16) ushort t[64][72];
  const int tid = threadIdx.x;
  const long bx = (long)blockIdx.x * 64;
  const long by = (long)blockIdx.y * 64;
#pragma unroll
  for (int i = 0; i < 2; ++i) {
    int row = (tid >> 3) + i * 32;
    int col = (tid & 7) * 8;
    *(short8*)(&t[row][col]) = *(const short8*)(in + (by + row) * 2048 + bx + col);
  }
  __syncthreads();
#pragma unroll
  for (int i = 0; i < 2; ++i) {
    int orow = (tid >> 3) + i * 32;
    int ocol = (tid & 7) * 8;
    short8 v;
#pragma unroll
    for (int j = 0; j < 8; ++j) v[j] = (short)t[ocol + j][orow];
    *(short8*)(out + (bx + orow) * 2048 + by + ocol) = v;
  }
}

// mask [q][kv] f32  ->  maskT [kv][q] bf16 (transposed + converted).
// 64x64 tiles; coalesced f32 reads, coalesced bf16 writes.
__global__ __launch_bounds__(256)
void maskT_k(const float* __restrict__ in, ushort* __restrict__ out) {
  __shared__ ushort t[64][72];   // t[kv_local][q_local]
  const int tid = threadIdx.x;
  const long q0 = (long)blockIdx.y * 64;  // row tile of in
  const long k0 = (long)blockIdx.x * 64;  // col tile of in
#pragma unroll
  for (int i = 0; i < 4; ++i) {
    int row = i * 16 + (tid >> 4);   // q local 0..63
    int col = (tid & 15) * 4;        // kv local
    float4 v = *(const float4*)(in + (q0 + row) * S + k0 + col);
    t[col + 0][row] = f2bf(v.x);
    t[col + 1][row] = f2bf(v.y);
    t[col + 2][row] = f2bf(v.z);
    t[col + 3][row] = f2bf(v.w);
  }
  __syncthreads();
#pragma unroll
  for (int i = 0; i < 2; ++i) {
    int row = i * 32 + (tid >> 3);   // kv local
    int col = (tid & 7) * 8;         // q local
    *(short8*)(out + (k0 + row) * S + q0 + col) = *(const short8*)(&t[row][col]);
  }
}

// Flash attention: 4-wave blocks (q-tile 128), 2 blocks/CU, XCD-aware head mapping.
// Swapped QK^T, double-buffered K/V, one barrier/tile, tree reductions,
// hazard-fenced MFMA->VALU boundaries, COALESCED bf16 maskT reads.
// Grid: 512. Block 256 = 4 waves x 32 q-rows.
__global__ __launch_bounds__(256)
void attn4_k(const ushort* __restrict__ Qself, const ushort* __restrict__ Qcross,
             const ushort* __restrict__ Kp, const ushort* __restrict__ Vt,
             const ushort* __restrict__ maskT, ushort* __restrict__ outf) {
  __shared__ __align__(16) ushort ldsK[2 * 64 * 128];   // [buf][kv][d] 256B rows, slot^=(row&15)
  __shared__ __align__(16) ushort ldsV[2 * 128 * 64];   // [buf][d][kv] 128B rows, slot^=(row&7)
  const int tid = threadIdx.x, lane = tid & 63, wid = tid >> 6;
  const int c31 = lane & 31, hi = lane >> 5;

  // XCD-aware decode: head h lives on XCD h%8; all blocks sharing head-pair
  // {h, h+8} K/V land on one XCD's L2.
  const int b = blockIdx.x;
  const int xcd = b & 7, j = b >> 3;
  const int h = xcd + 8 * (j & 1);
  const int blk = (j >> 1) & 1;       // 0=self 1=cross
  const int qt = j >> 2;              // 0..15, q-tile of 128 rows

  const ushort* Qp = blk ? Qcross : Qself;
  const int qbase = qt * 128 + wid * 32;
  const long qme = qbase + c31;  // this lane's q-row (owns P row q=c31)

  short8 qf[8];
#pragma unroll
  for (int ks = 0; ks < 8; ++ks)
    qf[ks] = *(const short8*)(Qp + qme * HID + h * HD + ks * 16 + hi * 8);

  f32x16 o[4] = {};   // O[q=(r&3)+8*(r>>2)+4*hi][d = dt*32 + c31]
  float m_r = -__builtin_inff(), l_r = 0.f;

  const float SC  = 0.08838834764831845f;   // 1/sqrt(128)
  const float L2E = 1.4426950408889634f;
  const float THR = 5.545177444479562f;     // 8*ln2 -> P <= 2^8

  const int kRow4 = lane >> 4, kSlot = lane & 15;
  const int vRow8 = lane >> 3, vSlot = lane & 7;
  // maskT column pointer for this lane: maskT[kv][qme]; lanes 0-31 read 64B
  // contiguous per kv-row (coalesced), hi=1 lanes read row kv+4.
  const ushort* mT = maskT + qme;

#define STAGE(BO, KV0) do {                                                       \
    _Pragma("unroll")                                                             \
    for (int i_ = 0; i_ < 4; ++i_) {                                              \
      int seg = i_ * 4 + wid;                                                     \
      int rk = seg * 4 + kRow4;                                                   \
      glds16(Kp + (long)((KV0) + rk) * HID + h * HD + ((kSlot ^ (rk & 15)) << 3), \
             ldsK + (BO) * 8192 + seg * 512);                                     \
      int rv = seg * 8 + vRow8;                                                   \
      glds16(Vt + (long)(h * HD + rv) * S + (KV0) + ((vSlot ^ (rv & 7)) << 3),    \
             ldsV + (BO) * 8192 + seg * 512);                                     \
    }                                                                             \
  } while (0)

  STAGE(0, 0);
  __syncthreads();

  for (int t = 0; t < 32; ++t) {
    const int bo = t & 1;
    const ushort* kb = ldsK + bo * 8192;
    const ushort* vb = ldsV + bo * 8192;
    if (t < 31) STAGE(bo ^ 1, (t + 1) * 64);  // prefetch next tile; drains at barrier
    const int kv0 = t * 64;

    // mask values, coalesced scalar bf16 loads; issued before MFMA so the
    // L2 latency hides under the QK^T cluster.
    ushort mvu0[16], mvu1[16];
#pragma unroll
    for (int r = 0; r < 16; ++r) {
      int krow = (r & 3) + 8 * (r >> 2) + 4 * hi;
      mvu0[r] = mT[(long)(kv0 + krow) * S];
      mvu1[r] = mT[(long)(kv0 + 32 + krow) * S];
    }

    // S^T = K @ Q^T : lane holds S[q=c31][kv = kvb*32 + (r&3)+8*(r>>2)+4*hi]
    f32x16 s0 = {}, s1 = {};
    __builtin_amdgcn_s_setprio(1);
#pragma unroll
    for (int ks = 0; ks < 8; ++ks) {
      int r0 = c31, r1 = 32 + c31;
      short8 kf0 = *(const short8*)(kb + r0 * 128 + (((ks * 2 + hi) ^ (r0 & 15)) << 3));
      short8 kf1 = *(const short8*)(kb + r1 * 128 + (((ks * 2 + hi) ^ (r1 & 15)) << 3));
      mfma32(s0, kf0, qf[ks]);
      mfma32(s1, kf1, qf[ks]);
    }
    __builtin_amdgcn_s_setprio(0);
    MFMA_FENCE();  // s0/s1 read by VALU below; s1 written by the LAST mfma

    // natural domain: tv = s*scale + mask  (one FMA per element)
#pragma unroll
    for (int r = 0; r < 16; ++r) {
      s0[r] = __builtin_fmaf(s0[r], SC, bf2f(mvu0[r]));
      s1[r] = __builtin_fmaf(s1[r], SC, bf2f(mvu1[r]));
    }

    // row max: pairwise tree (depth 5) + cross-half exchange
    float mx[16];
#pragma unroll
    for (int r = 0; r < 16; ++r) mx[r] = fmaxf(s0[r], s1[r]);
#pragma unroll
    for (int st = 8; st >= 1; st >>= 1)
#pragma unroll
      for (int i = 0; i < 8; ++i)
        if (i < st) mx[i] = fmaxf(mx[i], mx[i + st]);
    float pmax = fmaxf(mx[0], __shfl_xor(mx[0], 32));

    // defer-max: rescale O and l only when max grows by > THR (wave-uniform)
    if (!__all(pmax <= m_r + THR)) {
      float mnew = fmaxf(m_r, pmax);
      float alpha = __builtin_amdgcn_exp2f((m_r - mnew) * L2E);  // 0 on first tile
      m_r = mnew;
      l_r *= alpha;
#pragma unroll
      for (int r = 0; r < 16; ++r) {
        float alf = __shfl(alpha, (r & 3) + 8 * (r >> 2) + 4 * hi);
#pragma unroll
        for (int dt = 0; dt < 4; ++dt) o[dt][r] *= alf;
      }
    }

    // P = exp(tv - m) = exp2(fma(tv, L2E, -m*L2E)); f32 row-sum via tree
    const float nm = -m_r * L2E;
#pragma unroll
    for (int r = 0; r < 16; ++r) {
      s0[r] = __builtin_amdgcn_exp2f(__builtin_fmaf(s0[r], L2E, nm));
      s1[r] = __builtin_amdgcn_exp2f(__builtin_fmaf(s1[r], L2E, nm));
    }
    float sm[16];
#pragma unroll
    for (int r = 0; r < 16; ++r) sm[r] = s0[r] + s1[r];
#pragma unroll
    for (int st = 8; st >= 1; st >>= 1)
#pragma unroll
      for (int i = 0; i < 8; ++i)
        if (i < st) sm[i] += sm[i + st];
    l_r += sm[0] + __shfl_xor(sm[0], 32);

    // P -> bf16 A-frags: per 16-kv block, 4 cvt_pk + 2 permlane32_swap
    short8 pa[4];
#pragma unroll
    for (int kk = 0; kk < 4; ++kk) {
      const f32x16& sv = (kk < 2) ? s0 : s1;
      const int bq = (kk & 1) * 8;
      u32 x0 = cvtpk(sv[bq + 0], sv[bq + 1]);
      u32 x1 = cvtpk(sv[bq + 2], sv[bq + 3]);
      u32 y0 = cvtpk(sv[bq + 4], sv[bq + 5]);
      u32 y1 = cvtpk(sv[bq + 6], sv[bq + 7]);
      plswap(x0, y0);
      plswap(x1, y1);
      u32x4 tt; tt[0] = x0; tt[1] = x1; tt[2] = y0; tt[3] = y1;
      pa[kk] = __builtin_bit_cast(short8, tt);
    }
    // VALU(permlane) -> MFMA SrcA hazard padding
    asm volatile("s_nop 1");
    __builtin_amdgcn_sched_barrier(0);

    // O += P @ V
    __builtin_amdgcn_s_setprio(1);
#pragma unroll
    for (int dt = 0; dt < 4; ++dt) {
      int row = dt * 32 + c31;
#pragma unroll
      for (int kk = 0; kk < 4; ++kk) {
        short8 vf = *(const short8*)(vb + row * 64 + (((kk * 2 + hi) ^ (row & 7)) << 3));
        mfma32(o[dt], pa[kk], vf);
      }
    }
    __builtin_amdgcn_s_setprio(0);

    __syncthreads();  // next-tile stage drained + all waves done reading this buf
  }
#undef STAGE

  MFMA_FENCE();  // o[] read by VALU epilogue; o[3] written by the LAST mfma
#pragma unroll
  for (int r = 0; r < 16; ++r) {
    int qr = (r & 3) + 8 * (r >> 2) + 4 * hi;
    float linv = 1.0f / __shfl(l_r, qr);
    long orow = 2L * (qbase + qr) + blk;
#pragma unroll
    for (int dt = 0; dt < 4; ++dt)
      outf[orow * HID + h * HD + dt * 32 + c31] = f2bf(o[dt][r] * linv);
  }
}

extern "C" void kernel_launch(void* const* d_in, const int* in_sizes, int n_in,
                              void* d_out, int out_size, void* d_ws, size_t ws_size,
                              hipStream_t stream) {
  (void)in_sizes; (void)n_in; (void)out_size; (void)ws_size;
  const float* x_self  = (const float*)d_in[0];
  const float* x_cross = (const float*)d_in[1];
  const float* mask    = (const float*)d_in[2];
  const float* Wq      = (const float*)d_in[3];
  const float* Wk      = (const float*)d_in[4];
  const float* Wv      = (const float*)d_in[5];
  const float* Wo      = (const float*)d_in[6];

  uint8_t* w = (uint8_t*)d_ws;
  const size_t MB8 = (size_t)S * HID * sizeof(ushort);  // 8 MiB
  ushort* xs_bf   = (ushort*)(w + 0 * MB8);  // later reused as Vt
  ushort* xc_bf   = (ushort*)(w + 1 * MB8);
  ushort* Wq_bf   = (ushort*)(w + 2 * MB8);  // later reused as out_flat (16MB w/ Wk)
  ushort* Wk_bf   = (ushort*)(w + 3 * MB8);
  ushort* Wv_bf   = (ushort*)(w + 4 * MB8);
  ushort* Wo_bf   = (ushort*)(w + 5 * MB8);
  ushort* q_self  = (ushort*)(w + 6 * MB8);
  ushort* q_cross = (ushort*)(w + 7 * MB8);
  ushort* k_      = (ushort*)(w + 8 * MB8);
  ushort* v_      = (ushort*)(w + 9 * MB8);
  ushort* vt       = xs_bf;   // alias: xs/xc dead after projections
  ushort* out_flat = Wq_bf;   // alias: Wq/Wk bf16 dead after projections
  ushort* maskT    = v_;      // alias: v_ dead after V-transpose (8MB = 2048*2048*2B)

  CastArgs ca;
  ca.s[0] = x_self;  ca.d[0] = xs_bf;
  ca.s[1] = x_cross; ca.d[1] = xc_bf;
  ca.s[2] = Wq;      ca.d[2] = Wq_bf;
  ca.s[3] = Wk;      ca.d[3] = Wk_bf;
  ca.s[4] = Wv;      ca.d[4] = Wv_bf;
  ca.s[5] = Wo;      ca.d[5] = Wo_bf;
  cast6_k<<<dim3(4096, 6), 256, 0, stream>>>(ca);

  gemm_bt_k<0, 0><<<dim3(16, 32), 256, 0, stream>>>(xs_bf, Wq_bf, q_self, 4096, 2048, 2048);
  gemm_bt_k<0, 1><<<dim3(32, 16), 256, 0, stream>>>(xs_bf, Wk_bf, k_, 2048, 4096, 2048);

  transpose_bf16_k<<<dim3(32, 32), 256, 0, stream>>>(v_, vt);
  maskT_k<<<dim3(32, 32), 256, 0, stream>>>(mask, maskT);  // after v_ consumed

  attn4_k<<<dim3(512), 256, 0, stream>>>(q_self, q_cross, k_, vt, maskT, out_flat);

  gemm_bt_k<1, 0><<<dim3(16, 32), 256, 0, stream>>>(out_flat, Wo_bf, d_out, 4096, 2048, 2048);
}